// Round 10
// baseline (356.523 us; speedup 1.0000x reference)
//
#include <hip/hip_runtime.h>
#include <math.h>

// Problem constants
#define Bdim 32
#define Ndim 2048
#define Cdim 3
#define Kdim 20
#define Edim 64
#define NPART 27                 // 6 first moments + 21 second moments
#define NBLK1 2048               // k1 grid = 64 x 32
#define CNT (Bdim * Ndim * Kdim) // BN sample count = 1,310,720

#define NEG_INF __int_as_float(0xFF800000)

// Wave reduces via __builtin_amdgcn_update_dpp (mov_dpp + op). VERIFIED in
// R4/R5/R7/R8. R9 swapped these for "fused" single-instruction DPP inline asm
// (v_max_f32 dst, src, src row_ror:N) and FAILED correctness (absmax 5.97,
// pattern = corrupted BN stats). Mechanism undiagnosed (suspects: asm not
// convergent-marked -> movable across exec-divergent code; regalloc ties).
// DO NOT replace these with inline asm without a standalone lane-exact A/B.
#define DPPU(v, ctrl) \
  ((unsigned)__builtin_amdgcn_update_dpp((int)(v), (int)(v), (ctrl), 0xf, 0xf, false))
#define DPPF(v, ctrl) \
  (__int_as_float(__builtin_amdgcn_update_dpp(__float_as_int(v), __float_as_int(v), (ctrl), 0xf, 0xf, false)))

// Wave-wide max (u32); result valid in lane 63.
__device__ __forceinline__ unsigned red_max_u32_l63(unsigned v) {
  unsigned t;
  t = DPPU(v, 0x121); v = (v > t) ? v : t;  // row_ror:1
  t = DPPU(v, 0x122); v = (v > t) ? v : t;  // row_ror:2
  t = DPPU(v, 0x124); v = (v > t) ? v : t;  // row_ror:4
  t = DPPU(v, 0x128); v = (v > t) ? v : t;  // row_ror:8
  t = DPPU(v, 0x142); v = (v > t) ? v : t;  // row_bcast15
  t = DPPU(v, 0x143); v = (v > t) ? v : t;  // row_bcast31 -> lane63 global
  return v;
}

// Wave-wide max (f32, finite values + NEG_INF sentinel); result in lane 63.
__device__ __forceinline__ float red_max_f32_l63(float v) {
  float t;
  t = DPPF(v, 0x121); v = fmaxf(v, t);
  t = DPPF(v, 0x122); v = fmaxf(v, t);
  t = DPPF(v, 0x124); v = fmaxf(v, t);
  t = DPPF(v, 0x128); v = fmaxf(v, t);
  t = DPPF(v, 0x142); v = fmaxf(v, t);
  t = DPPF(v, 0x143); v = fmaxf(v, t);
  return v;
}

// Wave-wide sum; result valid in lane 63 only.
__device__ __forceinline__ float red_add_f32_l63(float v) {
  float t;
  t = DPPF(v, 0x121); v += t;
  t = DPPF(v, 0x122); v += t;
  t = DPPF(v, 0x124); v += t;
  t = DPPF(v, 0x128); v += t;
  t = DPPF(v, 0x142); v += t;
  t = DPPF(v, 0x143); v += t;
  return v;
}

__device__ __forceinline__ float sreadf(float v, int l) {
  return __int_as_float(__builtin_amdgcn_readlane(__float_as_int(v), l));
}

// ---------------------------------------------------------------------------
// Kernel 1: KNN top-20 per point + 27 edge-moment partial sums per block.
// 512 threads = 8 waves sharing one pts[] copy (33 KB -> 4 blocks/CU = 32
// waves/CU). Each wave owns 4 points:
//  - scan FUSED across the 4 points (one ds_read_b128 of pj feeds 4 top-3
//    updates -> 8 LDS reads/point; verified in R8)
//  - rounds SEQUENTIAL per point (R8 showed fusing rounds regresses: per-p
//    readlane/ballot/branch control flow serializes the chains anyway and
//    the extra live state + branch overhead cost 1.5x; verified in R7).
// Per-lane top-3 cache (float keys, slot index t as payload) + consumed
// bitmask; branchless owner-pop; rescan only on a lane's 3rd win.
// !!! DISTANCE EXPRESSION IS FROZEN: `dot = pi.x*pj.x + pi.y*pj.y + pi.z*pj.z;
// pd = 2.0f*dot - pi.w - pj.w` — R6 showed any re-association (explicit fmaf,
// reordered subtraction) flips near-tie selections vs the np reference and
// fails the absmax threshold. Do not "optimize" this arithmetic.
// ---------------------------------------------------------------------------
__global__ __launch_bounds__(512) void k1_knn_stats(
    const float* __restrict__ xyz, int* __restrict__ idx_out,
    float* __restrict__ partials) {
  __shared__ float4 pts[Ndim];       // {x, y, z, ||p||^2}  (32 KiB)
  __shared__ float red[8][NPART];

  const int b = blockIdx.y;
  const int tid = threadIdx.x;
  const float* xb = xyz + (size_t)b * Ndim * Cdim;

  // Stage xyz[b] into LDS
  float* sp = (float*)&pts[0];
  for (int g = tid; g < Ndim * Cdim; g += 512) {
    sp[(g / 3) * 4 + (g % 3)] = xb[g];
  }
  __syncthreads();
  for (int p = tid; p < Ndim; p += 512) {
    float4 q = pts[p];
    pts[p].w = q.x * q.x + q.y * q.y + q.z * q.z;
  }
  __syncthreads();

  const int w = tid >> 6;
  const int lane = tid & 63;

  float acc[NPART];
#pragma unroll
  for (int c = 0; c < NPART; ++c) acc[c] = 0.0f;

  const int i0 = blockIdx.x * 32 + w * 4;

  float4 pi[4];
#pragma unroll
  for (int p = 0; p < 4; ++p) pi[p] = pts[i0 + p];

  float h1[4], h2[4], h3[4];
  unsigned l1[4], l2[4], l3[4], mask[4];
#pragma unroll
  for (int p = 0; p < 4; ++p) {
    h1[p] = h2[p] = h3[p] = NEG_INF;
    l1[p] = l2[p] = l3[p] = 0u;
    mask[p] = 0u;
  }

  // Fused top-3 scan: one pj read feeds 4 points (verified R8)
#pragma unroll 4
  for (int t = 0; t < 32; ++t) {
    const float4 pj = pts[t * 64 + lane];
#pragma unroll
    for (int p = 0; p < 4; ++p) {
      const float dot = pi[p].x * pj.x + pi[p].y * pj.y + pi[p].z * pj.z;
      const float pd = 2.0f * dot - pi[p].w - pj.w;   // (FROZEN)
      const bool b1 = pd > h1[p];
      const bool b2 = pd > h2[p];
      const bool b3 = pd > h3[p];
      h3[p] = b3 ? (b2 ? h2[p] : pd) : h3[p];
      l3[p] = b3 ? (b2 ? l2[p] : (unsigned)t) : l3[p];
      h2[p] = b2 ? (b1 ? h1[p] : pd) : h2[p];
      l2[p] = b2 ? (b1 ? l1[p] : (unsigned)t) : l2[p];
      h1[p] = b1 ? pd : h1[p];
      l1[p] = b1 ? (unsigned)t : l1[p];
    }
  }

  // Rounds: sequential per point (p unrolled -> static register indexing)
#pragma unroll
  for (int p = 0; p < 4; ++p) {
    unsigned myJ = 0u;
    for (int r = 0; r < Kdim; ++r) {
      // 1) global max of heads (f32, exact), builtin-DPP VALU reduce
      const float bm = red_max_f32_l63(h1[p]);
      const float bestk = sreadf(bm, 63);

      // 2) winner: ballot of head==best; exact tie -> max (2047-j)
      const unsigned long long mb = __ballot(h1[p] == bestk);
      unsigned jwin;
      if ((mb & (mb - 1ull)) == 0ull) {            // single owner (common)
        const int wl = __ffsll((unsigned long long)mb) - 1;
        jwin = ((unsigned)__builtin_amdgcn_readlane((int)l1[p], wl)) * 64u +
               (unsigned)wl;
      } else {                                      // exact tie (rare), uniform
        unsigned cand =
            (h1[p] == bestk) ? (2047u - (l1[p] * 64u + (unsigned)lane)) : 0u;
        cand = red_max_u32_l63(cand);
        jwin = 2047u - (unsigned)__builtin_amdgcn_readlane((int)cand, 63);
      }
      if (lane == r) myJ = jwin;

      // 3) branchless owner-pop (rescan branch kept, exec-skipped)
      const bool win = ((unsigned)lane == (jwin & 63u));
      const bool pop = win && (h2[p] != NEG_INF);
      const bool resc = win && (h2[p] == NEG_INF);
      mask[p] |= win ? (1u << (jwin >> 6)) : 0u;
      h1[p] = pop ? h2[p] : h1[p];  l1[p] = pop ? l2[p] : l1[p];
      h2[p] = pop ? h3[p] : h2[p];  l2[p] = pop ? l3[p] : l2[p];
      h3[p] = pop ? NEG_INF : h3[p];
      if (resc) {
        float a1 = NEG_INF, a2 = NEG_INF, a3 = NEG_INF;
        unsigned c1 = 0u, c2 = 0u, c3 = 0u;
        for (int t = 0; t < 32; ++t) {
          if (mask[p] & (1u << t)) continue;
          const int j = t * 64 + lane;
          const float4 pj = pts[j];
          const float dot = pi[p].x * pj.x + pi[p].y * pj.y + pi[p].z * pj.z;
          const float pd = 2.0f * dot - pi[p].w - pj.w;   // (FROZEN)
          const bool b1 = pd > a1;
          const bool b2 = pd > a2;
          const bool b3 = pd > a3;
          a3 = b3 ? (b2 ? a2 : pd) : a3;  c3 = b3 ? (b2 ? c2 : (unsigned)t) : c3;
          a2 = b2 ? (b1 ? a1 : pd) : a2;  c2 = b2 ? (b1 ? c1 : (unsigned)t) : c2;
          a1 = b1 ? pd : a1;              c1 = b1 ? (unsigned)t : c1;
        }
        h1[p] = a1; l1[p] = c1; h2[p] = a2; l2[p] = c2; h3[p] = a3; l3[p] = c3;
      }
    }

    // Epilogue for this point: store indices + accumulate 27 edge moments
    if (lane < Kdim) {
      idx_out[((size_t)b * Ndim + (i0 + p)) * Kdim + lane] = (int)myJ;
      const float4 pj = pts[myJ];
      float ev[6];
      ev[0] = pi[p].x; ev[1] = pi[p].y; ev[2] = pi[p].z;
      ev[3] = pj.x - pi[p].x; ev[4] = pj.y - pi[p].y; ev[5] = pj.z - pi[p].z;
#pragma unroll
      for (int a = 0; a < 6; ++a) acc[a] += ev[a];
      int c = 6;
#pragma unroll
      for (int a = 0; a < 6; ++a)
#pragma unroll
        for (int d = a; d < 6; ++d) { acc[c] += ev[a] * ev[d]; ++c; }
    }
  }

  // Block reduction of the 27 accumulators (builtin-DPP adds; lane63 = sum)
#pragma unroll
  for (int c = 0; c < NPART; ++c) {
    const float v = red_add_f32_l63(acc[c]);
    if (lane == 63) red[w][c] = v;
  }
  __syncthreads();
  if (tid < NPART) {
    const int bid = blockIdx.y * gridDim.x + blockIdx.x;
    float v = 0.0f;
#pragma unroll
    for (int q = 0; q < 8; ++q) v += red[q][tid];
    partials[(size_t)bid * NPART + tid] = v;
  }
}

// ---------------------------------------------------------------------------
// Kernel 2: reduce 2048 partials (f64), fold 6x6 moments through W into
// per-channel BN scale/shift.
// ---------------------------------------------------------------------------
__global__ __launch_bounds__(256) void k2_bnstats(
    const float* __restrict__ partials, const float* __restrict__ W,
    const float* __restrict__ gamma, const float* __restrict__ beta,
    float* __restrict__ ss) {
  __shared__ double stat[NPART];
  __shared__ double red[4];
  const int tid = threadIdx.x;
  const int lane = tid & 63;
  const int w = tid >> 6;

  for (int c = 0; c < NPART; ++c) {
    double v = 0.0;
    for (int p = tid; p < NBLK1; p += 256) v += (double)partials[(size_t)p * NPART + c];
#pragma unroll
    for (int d = 1; d < 64; d <<= 1) v += __shfl_xor(v, d, 64);
    if (lane == 0) red[w] = v;
    __syncthreads();
    if (tid == 0) stat[c] = red[0] + red[1] + red[2] + red[3];
    __syncthreads();
  }

  if (tid < Edim) {
    const double inv = 1.0 / (double)CNT;
    double mu[6];
#pragma unroll
    for (int c = 0; c < 6; ++c) mu[c] = stat[c] * inv;
    double wv[6];
#pragma unroll
    for (int c = 0; c < 6; ++c) wv[c] = (double)W[tid * 6 + c];
    double m = 0.0;
#pragma unroll
    for (int c = 0; c < 6; ++c) m += wv[c] * mu[c];
    double q = 0.0;
    int s = 6;
#pragma unroll
    for (int a = 0; a < 6; ++a)
#pragma unroll
      for (int d = a; d < 6; ++d) {
        q += (a == d ? 1.0 : 2.0) * wv[a] * wv[d] * (stat[s] * inv);
        ++s;
      }
    const double var = q - m * m;
    const double rstd = 1.0 / sqrt(var + 1e-5);
    const float scale = (float)((double)gamma[tid] * rstd);
    const float shift = (float)((double)beta[tid] - m * rstd * (double)gamma[tid]);
    ss[tid] = scale;
    ss[Edim + tid] = shift;
  }
}

// ---------------------------------------------------------------------------
// Kernel 3: recompute h per (b,n,k,e), BN + hardswish, max over k, write
// out[b,e,n] coalesced via LDS transpose. 512 threads; lane = channel e.
// Neighbor index is wave-uniform -> readfirstlane to enable scalar loads.
// ---------------------------------------------------------------------------
__global__ __launch_bounds__(512) void k3_out(
    const float* __restrict__ xyz, const int* __restrict__ idx,
    const float* __restrict__ W, const float* __restrict__ ss,
    float* __restrict__ out) {
  __shared__ float4 pts[Ndim];   // 32 KiB: {x,y,z,unused}
  __shared__ float sm[128][65];  // 33 KiB
  const int b = blockIdx.y;
  const int n0 = blockIdx.x * 128;
  const int tid = threadIdx.x;
  const int w = tid >> 6;
  const int lane = tid & 63;
  const float* xb = xyz + (size_t)b * Ndim * Cdim;

  float* sp = (float*)&pts[0];
  for (int g = tid; g < Ndim * Cdim; g += 512) {
    sp[(g / 3) * 4 + (g % 3)] = xb[g];
  }
  __syncthreads();

  float wv[6];
#pragma unroll
  for (int c = 0; c < 6; ++c) wv[c] = W[lane * 6 + c];
  const float scale = ss[lane];
  const float shift = ss[Edim + lane];

  for (int s = 0; s < 16; ++s) {
    const int i = n0 + w * 16 + s;
    const float4 pi = pts[i];
    const float hbase = wv[0] * pi.x + wv[1] * pi.y + wv[2] * pi.z;
    const int* ip = idx + ((size_t)b * Ndim + i) * Kdim;
    float m = -INFINITY;
    for (int k = 0; k < Kdim; ++k) {
      const int j = __builtin_amdgcn_readfirstlane(ip[k]);
      const float4 pj = pts[j];
      const float h = hbase + wv[3] * (pj.x - pi.x) + wv[4] * (pj.y - pi.y) +
                      wv[5] * (pj.z - pi.z);
      const float a = h * scale + shift;
      const float r6 = fminf(fmaxf(a + 3.0f, 0.0f), 6.0f);
      const float hs = a * r6 * (1.0f / 6.0f);
      m = fmaxf(m, hs);
    }
    sm[w * 16 + s][lane] = m;
  }
  __syncthreads();

#pragma unroll
  for (int r = 0; r < 8; ++r) {
    const int e = r * 8 + w;
    out[((size_t)b * Edim + e) * Ndim + n0 + lane] = sm[lane][e];
    out[((size_t)b * Edim + e) * Ndim + n0 + 64 + lane] = sm[64 + lane][e];
  }
}

// ---------------------------------------------------------------------------
extern "C" void kernel_launch(void* const* d_in, const int* in_sizes, int n_in,
                              void* d_out, int out_size, void* d_ws, size_t ws_size,
                              hipStream_t stream) {
  const float* xyz = (const float*)d_in[0];
  const float* W = (const float*)d_in[1];
  const float* gamma = (const float*)d_in[2];
  const float* beta = (const float*)d_in[3];
  float* out = (float*)d_out;

  char* ws = (char*)d_ws;
  int* idx = (int*)ws;                                        // 5,242,880 B
  float* partials = (float*)(ws + (size_t)Bdim * Ndim * Kdim * 4);
  float* ss = (float*)(ws + (size_t)Bdim * Ndim * Kdim * 4 + (size_t)NBLK1 * NPART * 4);

  // Output 0: xyz passthrough
  hipMemcpyAsync(out, xyz, (size_t)Bdim * Ndim * Cdim * sizeof(float),
                 hipMemcpyDeviceToDevice, stream);

  k1_knn_stats<<<dim3(Ndim / 32, Bdim), 512, 0, stream>>>(xyz, idx, partials);
  k2_bnstats<<<1, 256, 0, stream>>>(partials, W, gamma, beta, ss);
  k3_out<<<dim3(Ndim / 128, Bdim), 512, 0, stream>>>(
      xyz, idx, W, ss, out + (size_t)Bdim * Ndim * Cdim);
}

// Round 11
// 254.836 us; speedup vs baseline: 1.3990x; 1.3990x over previous
//
#include <hip/hip_runtime.h>
#include <math.h>

// Problem constants
#define Bdim 32
#define Ndim 2048
#define Cdim 3
#define Kdim 20
#define Edim 64
#define NPART 27                 // 6 first moments + 21 second moments
#define NBLK1 2048               // k1 grid = 64 x 32
#define CNT (Bdim * Ndim * Kdim) // BN sample count = 1,310,720

#define NEG_INF __int_as_float(0xFF800000)

// Wave reduces via __builtin_amdgcn_update_dpp (mov_dpp + op). VERIFIED in
// R4/R5/R7/R8/R10. R9's inline-asm fused-DPP version FAILED correctness —
// do not replace without a standalone lane-exact A/B.
#define DPPU(v, ctrl) \
  ((unsigned)__builtin_amdgcn_update_dpp((int)(v), (int)(v), (ctrl), 0xf, 0xf, false))
#define DPPF(v, ctrl) \
  (__int_as_float(__builtin_amdgcn_update_dpp(__float_as_int(v), __float_as_int(v), (ctrl), 0xf, 0xf, false)))

// Wave-wide max (u32); result valid in lane 63.
__device__ __forceinline__ unsigned red_max_u32_l63(unsigned v) {
  unsigned t;
  t = DPPU(v, 0x121); v = (v > t) ? v : t;  // row_ror:1
  t = DPPU(v, 0x122); v = (v > t) ? v : t;  // row_ror:2
  t = DPPU(v, 0x124); v = (v > t) ? v : t;  // row_ror:4
  t = DPPU(v, 0x128); v = (v > t) ? v : t;  // row_ror:8
  t = DPPU(v, 0x142); v = (v > t) ? v : t;  // row_bcast15
  t = DPPU(v, 0x143); v = (v > t) ? v : t;  // row_bcast31 -> lane63 global
  return v;
}

// Wave-wide max (f32, finite values + NEG_INF sentinel); result in lane 63.
__device__ __forceinline__ float red_max_f32_l63(float v) {
  float t;
  t = DPPF(v, 0x121); v = fmaxf(v, t);
  t = DPPF(v, 0x122); v = fmaxf(v, t);
  t = DPPF(v, 0x124); v = fmaxf(v, t);
  t = DPPF(v, 0x128); v = fmaxf(v, t);
  t = DPPF(v, 0x142); v = fmaxf(v, t);
  t = DPPF(v, 0x143); v = fmaxf(v, t);
  return v;
}

// Wave-wide sum; result valid in lane 63 only.
__device__ __forceinline__ float red_add_f32_l63(float v) {
  float t;
  t = DPPF(v, 0x121); v += t;
  t = DPPF(v, 0x122); v += t;
  t = DPPF(v, 0x124); v += t;
  t = DPPF(v, 0x128); v += t;
  t = DPPF(v, 0x142); v += t;
  t = DPPF(v, 0x143); v += t;
  return v;
}

__device__ __forceinline__ float sreadf(float v, int l) {
  return __int_as_float(__builtin_amdgcn_readlane(__float_as_int(v), l));
}

// ---------------------------------------------------------------------------
// Kernel 1: KNN top-20 per point + 27 edge-moment partial sums per block.
// EXACT R7 structure (measured 189 us, VGPR 32, occupancy 71%): 512 threads
// = 8 waves sharing one pts[] copy; each wave handles 4 points SEQUENTIALLY
// (scan + rounds per point, scalar state). A/B-refuted alternatives — do not
// reintroduce:
//  * R8  fused 4-pt scan + fused rounds:     292 us (VGPR 44, occ 42%)
//  * R10 fused 4-pt scan + sequential rounds: 295 us (VGPR 48, occ 42%)
//  -> batched per-point array state itself collapses occupancy 71->42% and
//     time tracks occupancy (latency-bound). Keep scalar per-point state.
//  * R9 inline-asm fused-DPP reduces: WRONG RESULTS. Builtins only.
// !!! DISTANCE EXPRESSION IS FROZEN: `dot = pi.x*pj.x + pi.y*pj.y + pi.z*pj.z;
// pd = 2.0f*dot - pi.w - pj.w` — R6 showed any re-association flips near-tie
// selections vs the np reference and fails the absmax threshold.
// ---------------------------------------------------------------------------
__global__ __launch_bounds__(512) void k1_knn_stats(
    const float* __restrict__ xyz, int* __restrict__ idx_out,
    float* __restrict__ partials) {
  __shared__ float4 pts[Ndim];       // {x, y, z, ||p||^2}  (32 KiB)
  __shared__ float red[8][NPART];

  const int b = blockIdx.y;
  const int tid = threadIdx.x;
  const float* xb = xyz + (size_t)b * Ndim * Cdim;

  // Stage xyz[b] into LDS
  float* sp = (float*)&pts[0];
  for (int g = tid; g < Ndim * Cdim; g += 512) {
    sp[(g / 3) * 4 + (g % 3)] = xb[g];
  }
  __syncthreads();
  for (int p = tid; p < Ndim; p += 512) {
    float4 q = pts[p];
    pts[p].w = q.x * q.x + q.y * q.y + q.z * q.z;
  }
  __syncthreads();

  const int w = tid >> 6;
  const int lane = tid & 63;

  float acc[NPART];
#pragma unroll
  for (int c = 0; c < NPART; ++c) acc[c] = 0.0f;

  for (int s = 0; s < 4; ++s) {
    const int i = blockIdx.x * 32 + w * 4 + s;
    const float4 pi = pts[i];

    unsigned mask = 0u;                   // bit t -> slot j = t*64+lane consumed
    float h1 = NEG_INF, h2 = NEG_INF, h3 = NEG_INF;
    unsigned l1 = 0u, l2 = 0u, l3 = 0u;   // slot index t

    // Initial top-3 scan over this lane's 32 candidates
#pragma unroll 8
    for (int t = 0; t < 32; ++t) {
      const int j = t * 64 + lane;
      const float4 pj = pts[j];
      const float dot = pi.x * pj.x + pi.y * pj.y + pi.z * pj.z;
      const float pd = 2.0f * dot - pi.w - pj.w;   // (FROZEN)
      const bool b1 = pd > h1;
      const bool b2 = pd > h2;
      const bool b3 = pd > h3;
      h3 = b3 ? (b2 ? h2 : pd) : h3;  l3 = b3 ? (b2 ? l2 : (unsigned)t) : l3;
      h2 = b2 ? (b1 ? h1 : pd) : h2;  l2 = b2 ? (b1 ? l1 : (unsigned)t) : l2;
      h1 = b1 ? pd : h1;              l1 = b1 ? (unsigned)t : l1;
    }

    unsigned myJ = 0u;
    for (int r = 0; r < Kdim; ++r) {
      // 1) global max of heads (f32, exact), builtin-DPP VALU reduce
      const float bm = red_max_f32_l63(h1);
      const float bestk = sreadf(bm, 63);

      // 2) winner: ballot of head==best; exact tie -> max (2047-j)
      const unsigned long long mb = __ballot(h1 == bestk);
      unsigned jwin;
      if ((mb & (mb - 1ull)) == 0ull) {            // single owner (common)
        const int wl = __ffsll((unsigned long long)mb) - 1;
        jwin = ((unsigned)__builtin_amdgcn_readlane((int)l1, wl)) * 64u +
               (unsigned)wl;
      } else {                                      // exact tie (rare), uniform
        unsigned cand =
            (h1 == bestk) ? (2047u - (l1 * 64u + (unsigned)lane)) : 0u;
        cand = red_max_u32_l63(cand);
        jwin = 2047u - (unsigned)__builtin_amdgcn_readlane((int)cand, 63);
      }
      if (lane == r) myJ = jwin;

      // 3) owner lane pops: mark consumed, promote, or rescan on 3rd win
      if ((unsigned)lane == (jwin & 63u)) {
        mask |= (1u << (jwin >> 6));
        if (h2 != NEG_INF) {
          h1 = h2; l1 = l2; h2 = h3; l2 = l3; h3 = NEG_INF;
        } else {
          float a1 = NEG_INF, a2 = NEG_INF, a3 = NEG_INF;
          unsigned c1 = 0u, c2 = 0u, c3 = 0u;
          for (int t = 0; t < 32; ++t) {
            if (mask & (1u << t)) continue;
            const int j = t * 64 + lane;
            const float4 pj = pts[j];
            const float dot = pi.x * pj.x + pi.y * pj.y + pi.z * pj.z;
            const float pd = 2.0f * dot - pi.w - pj.w;   // (FROZEN)
            const bool b1 = pd > a1;
            const bool b2 = pd > a2;
            const bool b3 = pd > a3;
            a3 = b3 ? (b2 ? a2 : pd) : a3;  c3 = b3 ? (b2 ? c2 : (unsigned)t) : c3;
            a2 = b2 ? (b1 ? a1 : pd) : a2;  c2 = b2 ? (b1 ? c1 : (unsigned)t) : c2;
            a1 = b1 ? pd : a1;              c1 = b1 ? (unsigned)t : c1;
          }
          h1 = a1; l1 = c1; h2 = a2; l2 = c2; h3 = a3; l3 = c3;
        }
      }
    }

    if (lane < Kdim) {
      idx_out[((size_t)b * Ndim + i) * Kdim + lane] = (int)myJ;
      const float4 pj = pts[myJ];
      float ev[6];
      ev[0] = pi.x; ev[1] = pi.y; ev[2] = pi.z;
      ev[3] = pj.x - pi.x; ev[4] = pj.y - pi.y; ev[5] = pj.z - pi.z;
#pragma unroll
      for (int a = 0; a < 6; ++a) acc[a] += ev[a];
      int c = 6;
#pragma unroll
      for (int a = 0; a < 6; ++a)
#pragma unroll
        for (int d = a; d < 6; ++d) { acc[c] += ev[a] * ev[d]; ++c; }
    }
  }

  // Block reduction of the 27 accumulators (builtin-DPP adds; lane63 = sum)
#pragma unroll
  for (int c = 0; c < NPART; ++c) {
    const float v = red_add_f32_l63(acc[c]);
    if (lane == 63) red[w][c] = v;
  }
  __syncthreads();
  if (tid < NPART) {
    const int bid = blockIdx.y * gridDim.x + blockIdx.x;
    float v = 0.0f;
#pragma unroll
    for (int q = 0; q < 8; ++q) v += red[q][tid];
    partials[(size_t)bid * NPART + tid] = v;
  }
}

// ---------------------------------------------------------------------------
// Kernel 2: reduce 2048 partials (f64), fold 6x6 moments through W into
// per-channel BN scale/shift.
// ---------------------------------------------------------------------------
__global__ __launch_bounds__(256) void k2_bnstats(
    const float* __restrict__ partials, const float* __restrict__ W,
    const float* __restrict__ gamma, const float* __restrict__ beta,
    float* __restrict__ ss) {
  __shared__ double stat[NPART];
  __shared__ double red[4];
  const int tid = threadIdx.x;
  const int lane = tid & 63;
  const int w = tid >> 6;

  for (int c = 0; c < NPART; ++c) {
    double v = 0.0;
    for (int p = tid; p < NBLK1; p += 256) v += (double)partials[(size_t)p * NPART + c];
#pragma unroll
    for (int d = 1; d < 64; d <<= 1) v += __shfl_xor(v, d, 64);
    if (lane == 0) red[w] = v;
    __syncthreads();
    if (tid == 0) stat[c] = red[0] + red[1] + red[2] + red[3];
    __syncthreads();
  }

  if (tid < Edim) {
    const double inv = 1.0 / (double)CNT;
    double mu[6];
#pragma unroll
    for (int c = 0; c < 6; ++c) mu[c] = stat[c] * inv;
    double wv[6];
#pragma unroll
    for (int c = 0; c < 6; ++c) wv[c] = (double)W[tid * 6 + c];
    double m = 0.0;
#pragma unroll
    for (int c = 0; c < 6; ++c) m += wv[c] * mu[c];
    double q = 0.0;
    int s = 6;
#pragma unroll
    for (int a = 0; a < 6; ++a)
#pragma unroll
      for (int d = a; d < 6; ++d) {
        q += (a == d ? 1.0 : 2.0) * wv[a] * wv[d] * (stat[s] * inv);
        ++s;
      }
    const double var = q - m * m;
    const double rstd = 1.0 / sqrt(var + 1e-5);
    const float scale = (float)((double)gamma[tid] * rstd);
    const float shift = (float)((double)beta[tid] - m * rstd * (double)gamma[tid]);
    ss[tid] = scale;
    ss[Edim + tid] = shift;
  }
}

// ---------------------------------------------------------------------------
// Kernel 3: recompute h per (b,n,k,e), BN + hardswish, max over k, write
// out[b,e,n] coalesced via LDS transpose. 512 threads; lane = channel e.
// Neighbor index is wave-uniform -> readfirstlane enables scalar loads.
// (verified passing in R8/R10)
// ---------------------------------------------------------------------------
__global__ __launch_bounds__(512) void k3_out(
    const float* __restrict__ xyz, const int* __restrict__ idx,
    const float* __restrict__ W, const float* __restrict__ ss,
    float* __restrict__ out) {
  __shared__ float4 pts[Ndim];   // 32 KiB: {x,y,z,unused}
  __shared__ float sm[128][65];  // 33 KiB
  const int b = blockIdx.y;
  const int n0 = blockIdx.x * 128;
  const int tid = threadIdx.x;
  const int w = tid >> 6;
  const int lane = tid & 63;
  const float* xb = xyz + (size_t)b * Ndim * Cdim;

  float* sp = (float*)&pts[0];
  for (int g = tid; g < Ndim * Cdim; g += 512) {
    sp[(g / 3) * 4 + (g % 3)] = xb[g];
  }
  __syncthreads();

  float wv[6];
#pragma unroll
  for (int c = 0; c < 6; ++c) wv[c] = W[lane * 6 + c];
  const float scale = ss[lane];
  const float shift = ss[Edim + lane];

  for (int s = 0; s < 16; ++s) {
    const int i = n0 + w * 16 + s;
    const float4 pi = pts[i];
    const float hbase = wv[0] * pi.x + wv[1] * pi.y + wv[2] * pi.z;
    const int* ip = idx + ((size_t)b * Ndim + i) * Kdim;
    float m = -INFINITY;
    for (int k = 0; k < Kdim; ++k) {
      const int j = __builtin_amdgcn_readfirstlane(ip[k]);
      const float4 pj = pts[j];
      const float h = hbase + wv[3] * (pj.x - pi.x) + wv[4] * (pj.y - pi.y) +
                      wv[5] * (pj.z - pi.z);
      const float a = h * scale + shift;
      const float r6 = fminf(fmaxf(a + 3.0f, 0.0f), 6.0f);
      const float hs = a * r6 * (1.0f / 6.0f);
      m = fmaxf(m, hs);
    }
    sm[w * 16 + s][lane] = m;
  }
  __syncthreads();

#pragma unroll
  for (int r = 0; r < 8; ++r) {
    const int e = r * 8 + w;
    out[((size_t)b * Edim + e) * Ndim + n0 + lane] = sm[lane][e];
    out[((size_t)b * Edim + e) * Ndim + n0 + 64 + lane] = sm[64 + lane][e];
  }
}

// ---------------------------------------------------------------------------
extern "C" void kernel_launch(void* const* d_in, const int* in_sizes, int n_in,
                              void* d_out, int out_size, void* d_ws, size_t ws_size,
                              hipStream_t stream) {
  const float* xyz = (const float*)d_in[0];
  const float* W = (const float*)d_in[1];
  const float* gamma = (const float*)d_in[2];
  const float* beta = (const float*)d_in[3];
  float* out = (float*)d_out;

  char* ws = (char*)d_ws;
  int* idx = (int*)ws;                                        // 5,242,880 B
  float* partials = (float*)(ws + (size_t)Bdim * Ndim * Kdim * 4);
  float* ss = (float*)(ws + (size_t)Bdim * Ndim * Kdim * 4 + (size_t)NBLK1 * NPART * 4);

  // Output 0: xyz passthrough
  hipMemcpyAsync(out, xyz, (size_t)Bdim * Ndim * Cdim * sizeof(float),
                 hipMemcpyDeviceToDevice, stream);

  k1_knn_stats<<<dim3(Ndim / 32, Bdim), 512, 0, stream>>>(xyz, idx, partials);
  k2_bnstats<<<1, 256, 0, stream>>>(partials, W, gamma, beta, ss);
  k3_out<<<dim3(Ndim / 128, Bdim), 512, 0, stream>>>(
      xyz, idx, W, ss, out + (size_t)Bdim * Ndim * Cdim);
}